// Round 11
// baseline (424.858 us; speedup 1.0000x reference)
//
#include <hip/hip_runtime.h>
#include <hip/hip_bf16.h>
#include <hip/hip_cooperative_groups.h>

namespace cg = cooperative_groups;

#define N_NODES 50000
#define N_EDGES 800000
#define D 128
#define L_LAYERS 3
#define BN_EPS 1e-5f
#define NBUK 196          // buckets of 256 dst values
#define BIN_CHUNK 4096    // edges per bin block: 196*4096 >= 800000
#define NBIN_BLOCKS 196
#define BSTRIDE 5120      // fixed per-bucket region (words)
#define AROW 68           // LDS row stride in words
#define NTILES 782        // ceil(50000/64)

typedef __attribute__((ext_vector_type(8))) short short8;
typedef __attribute__((ext_vector_type(4))) float floatx4;
typedef __attribute__((ext_vector_type(4))) unsigned short ushort4v;

__device__ __forceinline__ unsigned short f2bf(float f) {
    unsigned u = __builtin_bit_cast(unsigned, f);
    u += 0x7FFFu + ((u >> 16) & 1u);
    return (unsigned short)(u >> 16);
}
__device__ __forceinline__ float bf2f(unsigned short h) {
    unsigned u = ((unsigned)h) << 16;
    return __builtin_bit_cast(float, u);
}
__device__ __forceinline__ float bf2f_lo(unsigned p) {
    return __builtin_bit_cast(float, p << 16);
}
__device__ __forceinline__ float bf2f_hi(unsigned p) {
    return __builtin_bit_cast(float, p & 0xFFFF0000u);
}

struct KArgs {
    const float* x;
    const int* ei32;
    const float* W1; const float* b1;
    const float* gamma; const float* beta;
    const float* W2; const float* b2;
    const float* eps;
    float* out;
    unsigned short* Xb;     // bf16 node features (gather input / layer output)
    unsigned* H16;          // gemm1 output, bf16 pairs (64 words/row)
    short* Wp;              // MFMA B-fragment weights
    int* rowptr;
    int* csr;
    unsigned* binned;
    int* bucketCursor;      // zero region: [NBUK] + stats[3*2*D] + queues[6]
    float* stats;
    int* queues;
};

// ---------------------------------------------------------------------------
// One kernel, 9 phases. phase < 0: run all phases with grid.sync() between
// (cooperative launch). phase >= 0: run only that phase (host serializes).
__global__ __launch_bounds__(1024) void mega_kernel(KArgs a, int phase, int layer) {
    __shared__ unsigned sbuf[64 * 132];   // 33792 B multi-purpose
    __shared__ float lsum2[2][D];
    __shared__ float lsq2[2][D];
    __shared__ float s_scale[D];
    __shared__ float s_shift[D];
    __shared__ int s_misc[4];
    __shared__ int s_flag;

    const int t = threadIdx.x;
    const int wave = t >> 6, lane = t & 63;
    const bool all = (phase < 0);

    // per-block edge-dtype detection (odd int32 words all zero -> int64)
    if (t == 0) s_flag = 1;
    __syncthreads();
    if (t < 256 && a.ei32[2 * t + 1] != 0) s_flag = 0;
    __syncthreads();
    const int isI64 = s_flag;

    const int gsz = gridDim.x * blockDim.x;
    const int gtid = blockIdx.x * blockDim.x + t;

    // ---- phase 0: zero control region, permute weights, convert x->bf16 ----
    if (all || phase == 0) {
        unsigned* zreg = (unsigned*)a.bucketCursor;
        const int zwords = NBUK + L_LAYERS * 2 * D + 6;
        for (int i = gtid; i < zwords; i += gsz) zreg[i] = 0u;
        for (int i = gtid; i < 6 * 2048; i += gsz) {
            int mat = i >> 11;
            int t2 = i & 2047;
            int kt = t2 >> 9, nt = (t2 >> 6) & 7, ln = t2 & 63;
            const float* W = (mat < 3) ? (a.W1 + (size_t)mat * D * D)
                                       : (a.W2 + (size_t)(mat - 3) * D * D);
            int kbase = kt * 32 + (ln >> 4) * 8;
            int n = nt * 16 + (ln & 15);
            short8 frag;
            #pragma unroll
            for (int j = 0; j < 8; j++) frag[j] = (short)f2bf(W[(kbase + j) * D + n]);
            *(short8*)(a.Wp + (size_t)mat * D * D + (size_t)t2 * 8) = frag;
        }
        for (int i = gtid; i < N_NODES * D / 4; i += gsz) {
            long long o = (long long)i * 4;
            float4 v = *(const float4*)(a.x + o);
            ushort4v u;
            u.x = f2bf(v.x); u.y = f2bf(v.y); u.z = f2bf(v.z); u.w = f2bf(v.w);
            *(ushort4v*)(a.Xb + o) = u;
        }
    }
    if (all) cg::this_grid().sync();

    // ---- phase 1: bin edges into bucket-ordered packed words ----
    if ((all || phase == 1) && blockIdx.x < NBIN_BLOCKS) {
        int* lhist = (int*)sbuf;
        int* gbase = (int*)sbuf + NBUK;
        for (int i = t; i < NBUK; i += 1024) lhist[i] = 0;
        __syncthreads();
        int e0 = blockIdx.x * BIN_CHUNK;
        unsigned w[4]; short bkt[4]; short lidx[4];
        #pragma unroll
        for (int i = 0; i < 4; i++) {
            int e = e0 + t + i * 1024;
            if (e < N_EDGES) {
                int s = isI64 ? (int)((const long long*)a.ei32)[e] : a.ei32[e];
                int d = isI64 ? (int)((const long long*)a.ei32)[(long long)N_EDGES + e]
                              : a.ei32[N_EDGES + e];
                int b = d >> 8;
                w[i] = ((unsigned)s << 8) | (unsigned)(d & 255);
                bkt[i] = (short)b;
                lidx[i] = (short)atomicAdd(&lhist[b], 1);
            } else {
                bkt[i] = -1;
            }
        }
        __syncthreads();
        for (int i = t; i < NBUK; i += 1024) {
            int c = lhist[i];
            gbase[i] = i * BSTRIDE + (c ? atomicAdd(&a.bucketCursor[i], c) : 0);
        }
        __syncthreads();
        #pragma unroll
        for (int i = 0; i < 4; i++)
            if (bkt[i] >= 0) a.binned[gbase[bkt[i]] + (int)lidx[i]] = w[i];
    }
    if (all) cg::this_grid().sync();

    // ---- phase 2: per-bucket CSR build (LDS scatter, coalesced rowptr) ----
    if ((all || phase == 2) && blockIdx.x < 256) {
        int* ls = (int*)sbuf;
        int* lhist = (int*)sbuf + 256;
        int* lcur = (int*)sbuf + 512;
        int b = blockIdx.x;
        int cv = 0;
        if (t < 256) { cv = (t < NBUK) ? a.bucketCursor[t] : 0; ls[t] = cv; }
        __syncthreads();
        for (int off = 1; off < 256; off <<= 1) {
            int u = (t < 256 && t >= off) ? ls[t - off] : 0;
            __syncthreads();
            if (t < 256) ls[t] += u;
            __syncthreads();
        }
        int base = (b == 0) ? 0 : ls[b - 1];
        int n = ls[b] - base;
        if (t < 256) lhist[t] = 0;
        __syncthreads();
        const unsigned* src = a.binned + (size_t)b * BSTRIDE;
        for (int i = t; i < n; i += 1024) atomicAdd(&lhist[src[i] & 255u], 1);
        __syncthreads();
        int v2 = (t < 256) ? lhist[t] : 0;
        if (t < 256) ls[t] = v2;
        __syncthreads();
        for (int off = 1; off < 256; off <<= 1) {
            int u = (t < 256 && t >= off) ? ls[t - off] : 0;
            __syncthreads();
            if (t < 256) ls[t] += u;
            __syncthreads();
        }
        if (t < 256) {
            int excl = ls[t] - v2;
            int dst = b * 256 + t;
            if (dst <= N_NODES) a.rowptr[dst] = base + excl;
            lcur[t] = excl;
        }
        __syncthreads();
        for (int i = t; i < n; i += 1024) {
            unsigned wv = src[i];
            int pos = atomicAdd(&lcur[wv & 255u], 1);
            a.csr[base + pos] = (int)(wv >> 8);
        }
    }
    if (all) cg::this_grid().sync();

    // ---- layers ----
    for (int l = 0; l < L_LAYERS; l++) {
        const short* WpA = a.Wp + (size_t)l * D * D;
        const short* WpB = a.Wp + (size_t)(3 + l) * D * D;
        const float* b1l = a.b1 + (size_t)l * D;
        const float* b2l = a.b2 + (size_t)l * D;
        const float* gml = a.gamma + (size_t)l * D;
        const float* btl = a.beta + (size_t)l * D;
        float* gsum = a.stats + (size_t)l * 2 * D;
        float* gsq = gsum + D;
        const int fin = (l == L_LAYERS - 1);

        // ---- phase 3: fused gather + GEMM1 (dynamic tile queue) ----
        if (all || (phase == 3 && layer == l)) {
            unsigned* lA = sbuf;
            float eps1 = 1.0f + a.eps[l];
            for (;;) {
                if (t == 0) { s_misc[0] = atomicAdd(&a.queues[l], 1); s_misc[1] = 0; }
                __syncthreads();
                int tile = s_misc[0];
                if (tile >= NTILES) break;
                int r0 = tile * 64;
                // gather: dynamic row queue, lane owns 2 columns
                for (;;) {
                    int r = 0;
                    if (lane == 0) r = atomicAdd(&s_misc[1], 1);
                    r = __shfl(r, 0);
                    if (r >= 64) break;
                    int row = r0 + r;
                    unsigned pack = 0;
                    if (row < N_NODES) {
                        int beg = a.rowptr[row], end = a.rowptr[row + 1];
                        float a0 = 0.f, a1 = 0.f, b0 = 0.f, b1 = 0.f;
                        float c0 = 0.f, c1 = 0.f, d0 = 0.f, d1 = 0.f;
                        for (int base = beg; base < end; base += 64) {
                            int n = end - base;
                            if (n > 64) n = 64;
                            int idx = (lane < n) ? a.csr[base + lane] : 0;
                            int j = 0;
                            for (; j + 7 < n; j += 8) {
                                int s0 = __shfl(idx, j);
                                int s1 = __shfl(idx, j + 1);
                                int s2 = __shfl(idx, j + 2);
                                int s3 = __shfl(idx, j + 3);
                                int s4 = __shfl(idx, j + 4);
                                int s5 = __shfl(idx, j + 5);
                                int s6 = __shfl(idx, j + 6);
                                int s7 = __shfl(idx, j + 7);
                                unsigned p0 = *(const unsigned*)(a.Xb + (long long)s0 * D + lane * 2);
                                unsigned p1 = *(const unsigned*)(a.Xb + (long long)s1 * D + lane * 2);
                                unsigned p2 = *(const unsigned*)(a.Xb + (long long)s2 * D + lane * 2);
                                unsigned p3 = *(const unsigned*)(a.Xb + (long long)s3 * D + lane * 2);
                                unsigned p4 = *(const unsigned*)(a.Xb + (long long)s4 * D + lane * 2);
                                unsigned p5 = *(const unsigned*)(a.Xb + (long long)s5 * D + lane * 2);
                                unsigned p6 = *(const unsigned*)(a.Xb + (long long)s6 * D + lane * 2);
                                unsigned p7 = *(const unsigned*)(a.Xb + (long long)s7 * D + lane * 2);
                                a0 += bf2f_lo(p0); a1 += bf2f_hi(p0);
                                b0 += bf2f_lo(p1); b1 += bf2f_hi(p1);
                                c0 += bf2f_lo(p2); c1 += bf2f_hi(p2);
                                d0 += bf2f_lo(p3); d1 += bf2f_hi(p3);
                                a0 += bf2f_lo(p4); a1 += bf2f_hi(p4);
                                b0 += bf2f_lo(p5); b1 += bf2f_hi(p5);
                                c0 += bf2f_lo(p6); c1 += bf2f_hi(p6);
                                d0 += bf2f_lo(p7); d1 += bf2f_hi(p7);
                            }
                            for (; j + 3 < n; j += 4) {
                                int s0 = __shfl(idx, j);
                                int s1 = __shfl(idx, j + 1);
                                int s2 = __shfl(idx, j + 2);
                                int s3 = __shfl(idx, j + 3);
                                unsigned p0 = *(const unsigned*)(a.Xb + (long long)s0 * D + lane * 2);
                                unsigned p1 = *(const unsigned*)(a.Xb + (long long)s1 * D + lane * 2);
                                unsigned p2 = *(const unsigned*)(a.Xb + (long long)s2 * D + lane * 2);
                                unsigned p3 = *(const unsigned*)(a.Xb + (long long)s3 * D + lane * 2);
                                a0 += bf2f_lo(p0); a1 += bf2f_hi(p0);
                                b0 += bf2f_lo(p1); b1 += bf2f_hi(p1);
                                c0 += bf2f_lo(p2); c1 += bf2f_hi(p2);
                                d0 += bf2f_lo(p3); d1 += bf2f_hi(p3);
                            }
                            for (; j < n; j++) {
                                int s0 = __shfl(idx, j);
                                unsigned p0 = *(const unsigned*)(a.Xb + (long long)s0 * D + lane * 2);
                                a0 += bf2f_lo(p0); a1 += bf2f_hi(p0);
                            }
                        }
                        float ax = a0 + b0 + c0 + d0;
                        float ay = a1 + b1 + c1 + d1;
                        unsigned pself = *(const unsigned*)(a.Xb + (long long)row * D + lane * 2);
                        float xv0 = bf2f_lo(pself), xv1 = bf2f_hi(pself);
                        float sa = ax * ax + ay * ay;
                        float sx = xv0 * xv0 + xv1 * xv1;
                        #pragma unroll
                        for (int mm = 32; mm >= 1; mm >>= 1) {
                            sa += __shfl_xor(sa, mm);
                            sx += __shfl_xor(sx, mm);
                        }
                        float ra = 1.0f / fmaxf(sqrtf(sa), 1e-12f);
                        float rx = eps1 / fmaxf(sqrtf(sx), 1e-12f);
                        float ox = ax * ra + xv0 * rx;
                        float oy = ay * ra + xv1 * rx;
                        pack = (unsigned)f2bf(ox) | ((unsigned)f2bf(oy) << 16);
                    }
                    lA[r * AROW + lane] = pack;
                }
                __syncthreads();

                // MFMA: wave -> (nt = wave&7, rg2 = wave>>3)
                int m = lane & 15, g = lane >> 4;
                int nt = wave & 7, rg2 = wave >> 3;
                int col = nt * 16 + m;
                float bcol = b1l[col];
                short8 bfr[4];
                #pragma unroll
                for (int kt = 0; kt < 4; kt++)
                    bfr[kt] = *(const short8*)(WpA + (size_t)((kt * 8 + nt) * 64 + lane) * 8);
                short8 a2[2][4];
                #pragma unroll
                for (int rt2 = 0; rt2 < 2; rt2++) {
                    const unsigned* lbase = lA + ((rg2 * 2 + rt2) * 16 + m) * AROW;
                    #pragma unroll
                    for (int kt = 0; kt < 4; kt++)
                        a2[rt2][kt] = *(const short8*)(lbase + kt * 16 + g * 4);
                }
                __syncthreads();   // lA free; becomes H staging tile

                unsigned short* hlds = (unsigned short*)lA;
                float s = 0.f, q = 0.f;
                #pragma unroll
                for (int rt2 = 0; rt2 < 2; rt2++) {
                    int rt = rg2 * 2 + rt2;
                    floatx4 acc = (floatx4){0.f, 0.f, 0.f, 0.f};
                    #pragma unroll
                    for (int kt = 0; kt < 4; kt++)
                        acc = __builtin_amdgcn_mfma_f32_16x16x32_bf16(a2[rt2][kt], bfr[kt], acc, 0, 0, 0);
                    #pragma unroll
                    for (int r = 0; r < 4; r++) {
                        int lrow = rt * 16 + g * 4 + r;
                        int grow = r0 + lrow;
                        float h = acc[r] + bcol;
                        hlds[lrow * (AROW * 2) + col] = f2bf(h);
                        if (grow < N_NODES) { s += h; q += h * h; }
                    }
                }
                s += __shfl_xor(s, 16); s += __shfl_xor(s, 32);
                q += __shfl_xor(q, 16); q += __shfl_xor(q, 32);
                if (lane < 16) { lsum2[rg2][col] = s; lsq2[rg2][col] = q; }
                __syncthreads();
                {
                    int crow = t >> 4, cq = t & 15;
                    if (r0 + crow < N_NODES) {
                        uint4 v = *(const uint4*)(lA + crow * AROW + cq * 4);
                        *(uint4*)(a.H16 + (size_t)(r0 + crow) * 64 + cq * 4) = v;
                    }
                }
                if (t < D) {
                    atomicAdd(&gsum[t], lsum2[0][t] + lsum2[1][t]);
                    atomicAdd(&gsq[t], lsq2[0][t] + lsq2[1][t]);
                }
                __syncthreads();
            }
        }
        if (all) cg::this_grid().sync();

        // ---- phase 4: GEMM2 + fused BN finalize/apply + ReLU ----
        if (all || (phase == 4 && layer == l)) {
            if (t < D) {
                const float invN = 1.0f / (float)N_NODES;
                float mu = gsum[t] * invN;
                float var = fmaxf(gsq[t] * invN - mu * mu, 0.f);
                float is = rsqrtf(var + BN_EPS);
                float sc = gml[t] * is;
                s_scale[t] = sc;
                s_shift[t] = btl[t] - mu * sc;
            }
            __syncthreads();
            int m = lane & 15, g = lane >> 4;
            int nt = wave & 7, rg2 = wave >> 3;
            int col = nt * 16 + m;
            float bcol = b2l[col];
            short8 bfr[4];
            #pragma unroll
            for (int kt = 0; kt < 4; kt++)
                bfr[kt] = *(const short8*)(WpB + (size_t)((kt * 8 + nt) * 64 + lane) * 8);
            for (;;) {
                if (t == 0) s_misc[2] = atomicAdd(&a.queues[3 + l], 1);
                __syncthreads();
                int tile = s_misc[2];
                if (tile >= NTILES) break;
                int r0 = tile * 64;
                #pragma unroll
                for (int rt2 = 0; rt2 < 2; rt2++) {
                    int rt = rg2 * 2 + rt2;
                    int arow = r0 + rt * 16 + m;
                    short8 aa[4];
                    if (arow < N_NODES) {
                        const unsigned short* hrow = (const unsigned short*)a.H16 + (size_t)arow * D;
                        #pragma unroll
                        for (int kt = 0; kt < 4; kt++) {
                            int koff = kt * 32 + g * 8;
                            short8 hv = *(const short8*)(hrow + koff);
                            #pragma unroll
                            for (int j = 0; j < 8; j++) {
                                float h = bf2f((unsigned short)hv[j]);
                                aa[kt][j] = (short)f2bf(fmaxf(h * s_scale[koff + j] + s_shift[koff + j], 0.f));
                            }
                        }
                    } else {
                        #pragma unroll
                        for (int kt = 0; kt < 4; kt++) aa[kt] = (short8)0;
                    }
                    floatx4 acc = (floatx4){0.f, 0.f, 0.f, 0.f};
                    #pragma unroll
                    for (int kt = 0; kt < 4; kt++)
                        acc = __builtin_amdgcn_mfma_f32_16x16x32_bf16(aa[kt], bfr[kt], acc, 0, 0, 0);
                    #pragma unroll
                    for (int r = 0; r < 4; r++) {
                        int lrow = rt * 16 + g * 4 + r;
                        if (fin) ((float*)sbuf)[lrow * 132 + col] = acc[r] + bcol;
                        else ((unsigned short*)sbuf)[lrow * 136 + col] = f2bf(fmaxf(acc[r] + bcol, 0.f));
                    }
                }
                __syncthreads();
                if (fin) {
                    #pragma unroll
                    for (int k = 0; k < 2; k++) {
                        int c = t + k * 1024;
                        int crow = c >> 5, cq = c & 31;
                        if (r0 + crow < N_NODES) {
                            float4 v = *(const float4*)((const float*)sbuf + crow * 132 + cq * 4);
                            *(float4*)(a.out + (size_t)(r0 + crow) * D + cq * 4) = v;
                        }
                    }
                } else {
                    int crow = t >> 4, cq = t & 15;
                    if (r0 + crow < N_NODES) {
                        uint4 v = *(const uint4*)(sbuf + crow * AROW + cq * 4);
                        *(uint4*)((unsigned*)a.Xb + (size_t)(r0 + crow) * 64 + cq * 4) = v;
                    }
                }
                __syncthreads();
            }
        }
        if (all && l != L_LAYERS - 1) cg::this_grid().sync();
    }
}

// ---------------------------------------------------------------------------
extern "C" void kernel_launch(void* const* d_in, const int* in_sizes, int n_in,
                              void* d_out, int out_size, void* d_ws, size_t ws_size,
                              hipStream_t stream) {
    KArgs ha;
    ha.x     = (const float*)d_in[0];
    ha.ei32  = (const int*)d_in[1];
    ha.W1    = (const float*)d_in[2];
    ha.b1    = (const float*)d_in[3];
    ha.gamma = (const float*)d_in[4];
    ha.beta  = (const float*)d_in[5];
    ha.W2    = (const float*)d_in[6];
    ha.b2    = (const float*)d_in[7];
    ha.eps   = (const float*)d_in[8];
    ha.out   = (float*)d_out;

    char* ws = (char*)d_ws;
    const size_t hbuf = (size_t)N_NODES * D * sizeof(short);   // 12.8 MB
    ha.Xb  = (unsigned short*)ws;
    ha.H16 = (unsigned*)(ws + hbuf);
    char* p = ws + 2 * hbuf;
    ha.Wp = (short*)p;              p += 6 * (size_t)D * D * sizeof(short);
    ha.rowptr = (int*)p;            p += (N_NODES + 1) * sizeof(int);
    ha.csr = (int*)p;               p += N_EDGES * sizeof(int);
    ha.binned = (unsigned*)p;       p += (size_t)NBUK * BSTRIDE * sizeof(unsigned);
    ha.bucketCursor = (int*)p;      p += NBUK * sizeof(int);
    ha.stats = (float*)p;           p += (size_t)L_LAYERS * 2 * D * sizeof(float);
    ha.queues = (int*)p;            p += 6 * sizeof(int);

    int dev = 0;
    (void)hipGetDevice(&dev);
    int coopAttr = 0;
    (void)hipDeviceGetAttribute(&coopAttr, hipDeviceAttributeCooperativeLaunch, dev);
    int maxB = 0;
    (void)hipOccupancyMaxActiveBlocksPerMultiprocessor(&maxB, mega_kernel, 1024, 0);
    int nblk = (maxB >= 2) ? 512 : 256;

    if (coopAttr && maxB >= 1) {
        int ph = -1, ly = 0;
        void* kargs[] = { (void*)&ha, (void*)&ph, (void*)&ly };
        (void)hipLaunchCooperativeKernel((void*)mega_kernel, dim3(nblk), dim3(1024),
                                         kargs, 0, stream);
    } else {
        mega_kernel<<<nblk, 1024, 0, stream>>>(ha, 0, 0);
        mega_kernel<<<nblk, 1024, 0, stream>>>(ha, 1, 0);
        mega_kernel<<<nblk, 1024, 0, stream>>>(ha, 2, 0);
        for (int l = 0; l < L_LAYERS; l++) {
            mega_kernel<<<nblk, 1024, 0, stream>>>(ha, 3, l);
            mega_kernel<<<nblk, 1024, 0, stream>>>(ha, 4, l);
        }
    }
}